// Round 15
// baseline (56.967 us; speedup 1.0000x reference)
//
#include <hip/hip_runtime.h>
#include <math.h>

#define NDET 16
#define NDIM 16
#define SPB  8     // samples per block (4 iterations x 2 samples)
#define NIT  4     // pipeline iterations per block

// ---- quad (4-lane) DPP broadcast: pure VALU, no LDS path -----------------
template<int OWNER>
__device__ __forceinline__ float bcast4f(float v) {
    constexpr int ctrl = OWNER * 0x55;  // quad_perm:[OWNER]*4
    return __int_as_float(
        __builtin_amdgcn_mov_dpp(__float_as_int(v), ctrl, 0xF, 0xF, true));
}

// ---- Householder QR step, COLUMN-INVOLUTION ORDER (R11/R13-verbatim) ------
template<int K>
__device__ __forceinline__ void qr_step(float (&c)[4][16], float &prod, float &sgn) {
    constexpr int OWNER = K & 3;
    constexpr int LC    = K >> 2;
    constexpr int JMIN  = K >> 2;

    float s0 = 0.0f, s1 = 0.0f;
    #pragma unroll
    for (int i = K; i < 16; i += 2)     s0 = fmaf(c[LC][i], c[LC][i], s0);
    #pragma unroll
    for (int i = K + 1; i < 16; i += 2) s1 = fmaf(c[LC][i], c[LC][i], s1);

    const float n2    = bcast4f<OWNER>(s0 + s1);
    const float xK    = bcast4f<OWNER>(c[LC][K]);
    const float alpha = __builtin_amdgcn_sqrtf(n2);          // ||x|| > 0 a.s.
    const float vK    = xK + copysignf(alpha, xK);           // |vK| = alpha+|xK|
    const float beta  = __builtin_amdgcn_rcpf(alpha * fabsf(vK));
    prod *= alpha;
    sgn = (xK < 0.0f) ? -sgn : sgn;

    float bv[16];
    bv[K] = vK;
    #pragma unroll
    for (int i = K + 1; i < 16; ++i) bv[i] = bcast4f<OWNER>(c[LC][i]);

    #pragma unroll
    for (int j = JMIN; j < 4; ++j) {
        float w0 = bv[K] * c[j][K], w1 = 0.0f;
        #pragma unroll
        for (int i = K + 1; i < 16; i += 2) w0 = fmaf(bv[i], c[j][i], w0);
        #pragma unroll
        for (int i = K + 2; i < 16; i += 2) w1 = fmaf(bv[i], c[j][i], w1);
        const float t = (w0 + w1) * beta;
        #pragma unroll
        for (int i = K; i < 16; ++i)
            c[j][i] = fmaf(-t, bv[i], c[j][i]);
    }
}

template<int K>
__device__ __forceinline__ void qr_all(float (&c)[4][16], float &prod, float &sgn) {
    qr_step<K>(c, prod, sgn);
    if constexpr (K < 14) qr_all<K + 1>(c, prod, sgn);
}

// Lane-specialized (R13) + software-pipelined persistent blocks:
// quad 2g -> matrix A of det g, quad 2g+1 -> matrix B. Each block runs NIT
// iterations of 2 samples; iteration i+1's 16 float4 loads are ISSUED before
// iteration i's QR so each wave hides HBM latency under its own compute.
__global__ __launch_bounds__(256) void logabssumdet_kernel(
    const float* __restrict__ a,
    const float* __restrict__ b,
    const float* __restrict__ w,
    float* __restrict__ out,
    int n_samples)
{
    const int tid    = threadIdx.x;
    const int lane4  = tid & 3;
    const int quad   = tid >> 2;                    // 0..63 in block
    const int half   = quad & 1;                    // 0 -> A, 1 -> B
    const int det_l  = quad >> 1;                   // 0..31 (2 samples x 16 dets)
    const int n_mats = n_samples * NDET;
    const float* const src = half ? b : a;

    __shared__ float sx[2][64];     // parity-double-buffered per-quad results
    __shared__ float ss[2][64];

    // ---- prologue: load iteration 0 into the prefetch buffer --------------
    float4 nxt[16];
    {
        const int mat_id = blockIdx.x * (SPB * NDET) + det_l;
        if (mat_id < n_mats) {
            const float4* mb =
                reinterpret_cast<const float4*>(src + (size_t)mat_id * (NDIM * NDIM)) + lane4;
            #pragma unroll
            for (int i = 0; i < 16; ++i) nxt[i] = mb[i * 4];
        }
    }

    #pragma unroll 1
    for (int it = 0; it < NIT; ++it) {
        const int mat_id = blockIdx.x * (SPB * NDET) + it * 32 + det_l;
        const bool valid = (mat_id < n_mats);
        const int par = it & 1;

        // rename prefetch buffer -> working matrix (register renaming, free)
        float c[4][16];
        #pragma unroll
        for (int i = 0; i < 16; ++i) {
            c[0][i] = nxt[i].x; c[1][i] = nxt[i].y;
            c[2][i] = nxt[i].z; c[3][i] = nxt[i].w;
        }

        // issue NEXT iteration's loads before this iteration's compute
        if (it + 1 < NIT) {
            const int nmat = mat_id + 32;
            if (nmat < n_mats) {
                const float4* mb =
                    reinterpret_cast<const float4*>(src + (size_t)nmat * (NDIM * NDIM)) + lane4;
                #pragma unroll
                for (int i = 0; i < 16; ++i) nxt[i] = mb[i * 4];
            }
        }

        // ---- QR factorization (R13-verbatim math) --------------------------
        float x = 0.0f, sgn = 1.0f;
        if (valid) {
            float prod = 1.0f;
            qr_all<0>(c, prod, sgn);                // 15 reflections
            prod *= bcast4f<3>(c[3][15]);           // column perm(15)=15 remainder
            x = __logf(fabsf(prod));
            sgn = (prod < 0.0f) ? -sgn : sgn;
        }

        if (lane4 == 0) { sx[par][quad] = x; ss[par][quad] = sgn; }
        __syncthreads();

        // 2 samples per iteration; threads 0,1 finish the 16-det LSE.
        // Parity buffers make it safe for other threads to run ahead into
        // iteration it+1 (they write parity par^1) while these threads read.
        if (tid < 2) {
            const int sample = blockIdx.x * SPB + it * 2 + tid;
            if (sample < n_samples) {
                const int base = tid * 2 * NDET;    // 32 quad entries per sample
                float xmax = -INFINITY;
                float xs[NDET], gs[NDET];
                #pragma unroll
                for (int d = 0; d < NDET; ++d) {
                    xs[d] = sx[par][base + 2 * d] + sx[par][base + 2 * d + 1];
                    gs[d] = ss[par][base + 2 * d] * ss[par][base + 2 * d + 1];
                    xmax  = fmaxf(xmax, xs[d]);
                }
                float sum = 0.0f;
                #pragma unroll
                for (int d = 0; d < NDET; ++d)
                    sum += gs[d] * __expf(xs[d] - xmax) * w[d];
                out[sample] = __logf(fabsf(sum)) + xmax;
                out[n_samples + sample] = (sum > 0.0f) ? 1.0f : ((sum < 0.0f) ? -1.0f : 0.0f);
            }
        }
    }
}

extern "C" void kernel_launch(void* const* d_in, const int* in_sizes, int n_in,
                              void* d_out, int out_size, void* d_ws, size_t ws_size,
                              hipStream_t stream)
{
    const float* a = (const float*)d_in[0];
    const float* b = (const float*)d_in[1];
    const float* w = (const float*)d_in[2];
    float* out = (float*)d_out;

    const int n_samples = in_sizes[0] / (NDET * NDIM * NDIM);
    const int blocks = (n_samples + SPB - 1) / SPB;   // 8 samples per block
    logabssumdet_kernel<<<blocks, 256, 0, stream>>>(a, b, w, out, n_samples);
}

// Round 16
// 51.262 us; speedup vs baseline: 1.1113x; 1.1113x over previous
//
#include <hip/hip_runtime.h>
#include <math.h>

#define NDET 16
#define NDIM 16
#define NIT  2     // samples per wave

// ---- quad (4-lane) DPP broadcast: pure VALU, no LDS path -----------------
template<int OWNER>
__device__ __forceinline__ float bcast4f(float v) {
    constexpr int ctrl = OWNER * 0x55;  // quad_perm:[OWNER]*4
    return __int_as_float(
        __builtin_amdgcn_mov_dpp(__float_as_int(v), ctrl, 0xF, 0xF, true));
}

// ---- Householder QR step, COLUMN-INVOLUTION ORDER (R11-verbatim math) -----
template<int K>
__device__ __forceinline__ void qr_step(float (&c)[4][16], float &prod, float &sgn) {
    constexpr int OWNER = K & 3;
    constexpr int LC    = K >> 2;
    constexpr int JMIN  = K >> 2;

    float s0 = 0.0f, s1 = 0.0f;
    #pragma unroll
    for (int i = K; i < 16; i += 2)     s0 = fmaf(c[LC][i], c[LC][i], s0);
    #pragma unroll
    for (int i = K + 1; i < 16; i += 2) s1 = fmaf(c[LC][i], c[LC][i], s1);

    const float n2    = bcast4f<OWNER>(s0 + s1);
    const float xK    = bcast4f<OWNER>(c[LC][K]);
    const float alpha = __builtin_amdgcn_sqrtf(n2);          // ||x|| > 0 a.s.
    const float vK    = xK + copysignf(alpha, xK);           // |vK| = alpha+|xK|
    const float beta  = __builtin_amdgcn_rcpf(alpha * fabsf(vK));
    prod *= alpha;
    sgn = (xK < 0.0f) ? -sgn : sgn;

    float bv[16];
    bv[K] = vK;
    #pragma unroll
    for (int i = K + 1; i < 16; ++i) bv[i] = bcast4f<OWNER>(c[LC][i]);

    #pragma unroll
    for (int j = JMIN; j < 4; ++j) {
        float w0 = bv[K] * c[j][K], w1 = 0.0f;
        #pragma unroll
        for (int i = K + 1; i < 16; i += 2) w0 = fmaf(bv[i], c[j][i], w0);
        #pragma unroll
        for (int i = K + 2; i < 16; i += 2) w1 = fmaf(bv[i], c[j][i], w1);
        const float t = (w0 + w1) * beta;
        #pragma unroll
        for (int i = K; i < 16; ++i)
            c[j][i] = fmaf(-t, bv[i], c[j][i]);
    }
}

template<int K>
__device__ __forceinline__ void qr_all(float (&c)[4][16], float &prod, float &sgn) {
    qr_step<K>(c, prod, sgn);
    if constexpr (K < 14) qr_all<K + 1>(c, prod, sgn);
}

// SELF-PACED WAVES, NO BARRIERS: wave = 16 quads = 16 dets = ONE sample per
// iteration; each quad factorizes its det's A then B (rolled m-loop, one QR
// body in I-cache). Register prefetch (nxt[16]) of the next matrix is issued
// BEFORE each QR (pinned by sched_barrier) so each wave hides HBM latency
// under its own compute. The 16-det LSE is intra-wave via a per-wave LDS
// region + lgkmcnt(0) — NO __syncthreads anywhere, so waves drift out of
// phase and memory stays busy during other waves' compute (anti phase-lock).
__global__ __launch_bounds__(256) void logabssumdet_kernel(
    const float* __restrict__ a,
    const float* __restrict__ b,
    const float* __restrict__ w,
    float* __restrict__ out,
    int n_samples)
{
    const int tid   = threadIdx.x;
    const int lane4 = tid & 3;
    const int quad  = (tid >> 2) & 15;        // quad within wave = det index
    const int wid   = tid >> 6;               // wave id 0..3
    const int s0    = (blockIdx.x * 4 + wid) * NIT;

    __shared__ float sxw[4][16];              // per-wave private regions
    __shared__ float ssw[4][16];

    // ---- prologue: prefetch A of first sample -----------------------------
    float4 nxt[16];
    {
        const int sc = (s0 < n_samples) ? s0 : (n_samples - 1);
        const float4* p = reinterpret_cast<const float4*>(
            a + ((size_t)sc * NDET + quad) * (NDIM * NDIM)) + lane4;
        #pragma unroll
        for (int i = 0; i < 16; ++i) nxt[i] = p[i * 4];
    }

    #pragma unroll 1
    for (int it = 0; it < NIT; ++it) {
        const int s = s0 + it;
        float x = 0.0f, sg = 1.0f;

        #pragma unroll 1                       // ONE QR body in I-cache
        for (int m = 0; m < 2; ++m) {
            // rename prefetch buffer -> working matrix (compiler inserts the
            // vmcnt wait here; in steady state the loads landed during the
            // previous QR, so no stall)
            float c[4][16];
            #pragma unroll
            for (int i = 0; i < 16; ++i) {
                c[0][i] = nxt[i].x; c[1][i] = nxt[i].y;
                c[2][i] = nxt[i].z; c[3][i] = nxt[i].w;
            }

            // issue next matrix's 16 loads (B of this sample, or A of next)
            if (!(it == NIT - 1 && m == 1)) {
                const float* nsrc = (m == 0) ? b : a;
                int ns = (m == 0) ? s : (s + 1);
                ns = (ns < n_samples) ? ns : (n_samples - 1);
                const float4* p = reinterpret_cast<const float4*>(
                    nsrc + ((size_t)ns * NDET + quad) * (NDIM * NDIM)) + lane4;
                #pragma unroll
                for (int i = 0; i < 16; ++i) nxt[i] = p[i * 4];
            }
            // pin prefetch issue ABOVE the QR (R6 lesson: the scheduler
            // otherwise sinks the loads to their use and serializes)
            __builtin_amdgcn_sched_barrier(0);

            float prod = 1.0f;
            qr_all<0>(c, prod, sg);            // 15 reflections (R11 math)
            prod *= bcast4f<3>(c[3][15]);      // column perm(15)=15 remainder
            x += __logf(fabsf(prod));
            sg = (prod < 0.0f) ? -sg : sg;
        }

        // ---- intra-wave LSE epilogue (no __syncthreads) --------------------
        if (lane4 == 0) { sxw[wid][quad] = x; ssw[wid][quad] = sg; }
        asm volatile("s_waitcnt lgkmcnt(0)" ::: "memory");  // writes visible wave-wide

        if (s < n_samples) {
            float xmax = -INFINITY;
            float xs[NDET], gs[NDET];
            #pragma unroll
            for (int d = 0; d < NDET; ++d) {   // broadcast reads, all lanes
                xs[d] = sxw[wid][d];
                gs[d] = ssw[wid][d];
                xmax  = fmaxf(xmax, xs[d]);
            }
            float sum = 0.0f;
            #pragma unroll
            for (int d = 0; d < NDET; ++d)
                sum += gs[d] * __expf(xs[d] - xmax) * w[d];
            if ((tid & 63) == 0) {             // lane 0 of the wave
                out[s] = __logf(fabsf(sum)) + xmax;
                out[n_samples + s] = (sum > 0.0f) ? 1.0f : ((sum < 0.0f) ? -1.0f : 0.0f);
            }
        }
        // reads above are in-order with next iteration's ds_writes (same-wave
        // DS ops retire in order; the next lgkmcnt(0) covers the hazard)
    }
}

extern "C" void kernel_launch(void* const* d_in, const int* in_sizes, int n_in,
                              void* d_out, int out_size, void* d_ws, size_t ws_size,
                              hipStream_t stream)
{
    const float* a = (const float*)d_in[0];
    const float* b = (const float*)d_in[1];
    const float* w = (const float*)d_in[2];
    float* out = (float*)d_out;

    const int n_samples = in_sizes[0] / (NDET * NDIM * NDIM);
    // 4 waves/WG, NIT samples per wave
    const int blocks = (n_samples + 4 * NIT - 1) / (4 * NIT);
    logabssumdet_kernel<<<blocks, 256, 0, stream>>>(a, b, w, out, n_samples);
}

// Round 17
// 46.992 us; speedup vs baseline: 1.2123x; 1.0909x over previous
//
#include <hip/hip_runtime.h>
#include <math.h>

#define NDET 16
#define NDIM 16

typedef float v2f __attribute__((ext_vector_type(2)));

// ---- forced packed dual-FP32 FMA (VOP3P, full-rate on CDNA4) --------------
// R14 proved __builtin_elementwise_fma scalarizes (VGPR/absmax unchanged);
// inline asm guarantees v_pk_fma_f32: 2 FMAs per instruction.
__device__ __forceinline__ v2f pk_fma(v2f a, v2f b, v2f c) {
    v2f d;
    asm("v_pk_fma_f32 %0, %1, %2, %3" : "=v"(d) : "v"(a), "v"(b), "v"(c));
    return d;
}

// ---- quad (4-lane) DPP broadcast: pure VALU, no LDS path -----------------
template<int OWNER>
__device__ __forceinline__ float bcast4f(float v) {
    constexpr int ctrl = OWNER * 0x55;  // quad_perm:[OWNER]*4
    return __int_as_float(
        __builtin_amdgcn_mov_dpp(__float_as_int(v), ctrl, 0xF, 0xF, true));
}

// ---- Householder QR step, involution order, ROW-PAIR PACKED ---------------
// Math = R11/R13 (proven): step K eliminates global column perm(K) =
// ((K&3)<<2)|(K>>2); owner lane = K&3, local col = K>>2, retired local cols
// j < K>>2 on every lane. Rows packed in pairs: cp[4][8].
template<int K>
__device__ __forceinline__ void qr_step(v2f (&cp)[4][8], float &prod, float &sgn) {
    constexpr int OWNER = K & 3;        // lane owning column perm(K)
    constexpr int LC    = K >> 2;       // its local column index
    constexpr int JMIN  = K >> 2;       // first possibly-active local column
    constexpr int RP    = K >> 1;       // pair containing row K
    constexpr int R0    = (K + 1) >> 1; // first fully-active pair

    // ---- ||x||^2 over rows K..15 (packed + odd-row fixup)
    v2f nacc = {0.0f, 0.0f};
    #pragma unroll
    for (int r = R0; r < 8; ++r)
        nacc = pk_fma(cp[LC][r], cp[LC][r], nacc);
    float nsum = nacc.x + nacc.y;
    if constexpr (K & 1) {
        const float e = cp[LC][RP].y;   // row K sits in .y of straddling pair
        nsum = fmaf(e, e, nsum);
    }

    float xKl;
    if constexpr (K & 1) xKl = cp[LC][RP].y; else xKl = cp[LC][RP].x;

    const float n2    = bcast4f<OWNER>(nsum);
    const float xK    = bcast4f<OWNER>(xKl);
    const float alpha = __builtin_amdgcn_sqrtf(n2);          // ||x|| > 0 a.s.
    const float vK    = xK + copysignf(alpha, xK);           // |vK| = alpha+|xK|
    const float beta  = __builtin_amdgcn_rcpf(alpha * fabsf(vK));
    prod *= alpha;
    sgn = (xK < 0.0f) ? -sgn : sgn;

    // ---- packed reflector bvp[RP..7]; row < K zeroed within pair RP
    v2f bvp[8];
    if constexpr (K & 1) {
        bvp[RP].x = 0.0f;               // row K-1 masked out
        bvp[RP].y = vK;                 // row K
    } else {
        bvp[RP].x = vK;                              // row K
        bvp[RP].y = bcast4f<OWNER>(cp[LC][RP].y);    // row K+1
    }
    #pragma unroll
    for (int r = RP + 1; r < 8; ++r) {
        bvp[r].x = bcast4f<OWNER>(cp[LC][r].x);
        bvp[r].y = bcast4f<OWNER>(cp[LC][r].y);
    }

    // ---- apply H to local columns JMIN..3 (packed dot + packed update)
    #pragma unroll
    for (int j = JMIN; j < 4; ++j) {
        v2f wacc = {0.0f, 0.0f};
        #pragma unroll
        for (int r = RP; r < 8; ++r)
            wacc = pk_fma(bvp[r], cp[j][r], wacc);
        const float t = (wacc.x + wacc.y) * beta;
        const v2f nt = {-t, -t};
        #pragma unroll
        for (int r = RP; r < 8; ++r)
            cp[j][r] = pk_fma(nt, bvp[r], cp[j][r]);
    }
}

template<int K>
__device__ __forceinline__ void qr_all(v2f (&cp)[4][8], float &prod, float &sgn) {
    qr_step<K>(cp, prod, sgn);
    if constexpr (K < 14) qr_all<K + 1>(cp, prod, sgn);
}

// LANE SPECIALIZATION shell (R13/R14, passed): quad 2g -> matrix A of det g,
// quad 2g+1 -> matrix B. 256 threads = 64 quads = 32 dets = 2 samples.
__global__ __launch_bounds__(256) void logabssumdet_kernel(
    const float* __restrict__ a,
    const float* __restrict__ b,
    const float* __restrict__ w,
    float* __restrict__ out,
    int n_samples)
{
    const int tid    = threadIdx.x;
    const int lane4  = tid & 3;
    const int quad   = tid >> 2;                    // 0..63 in block
    const int half   = quad & 1;                    // 0 -> A, 1 -> B
    const int det_l  = quad >> 1;                   // 0..31 local det index
    const int mat_id = blockIdx.x * 32 + det_l;     // = sample*16 + det
    const int n_mats = n_samples * NDET;

    __shared__ float sx[64];    // per-quad: log|det(half)|
    __shared__ float ss[64];    // per-quad: sign(half)

    float x = 0.0f, sgn = 1.0f;

    if (mat_id < n_mats) {
        const float* src = half ? b : a;
        const float4* mb =
            reinterpret_cast<const float4*>(src + (size_t)mat_id * (NDIM * NDIM)) + lane4;

        v2f cp[4][8];                               // [local col][row pair]
        #pragma unroll
        for (int i = 0; i < 16; ++i) {
            const float4 v = mb[i * 4];             // 64B contiguous per quad
            if ((i & 1) == 0) {
                cp[0][i >> 1].x = v.x; cp[1][i >> 1].x = v.y;
                cp[2][i >> 1].x = v.z; cp[3][i >> 1].x = v.w;
            } else {
                cp[0][i >> 1].y = v.x; cp[1][i >> 1].y = v.y;
                cp[2][i >> 1].y = v.z; cp[3][i >> 1].y = v.w;
            }
        }

        float prod = 1.0f;                          // product of alpha_K (>0)
        qr_all<0>(cp, prod, sgn);                   // 15 reflections
        prod *= bcast4f<3>(cp[3][7].y);             // column perm(15)=15, row 15

        x = __logf(fabsf(prod));                    // f32-range safe (proven)
        sgn = (prod < 0.0f) ? -sgn : sgn;
    }

    if (lane4 == 0) { sx[quad] = x; ss[quad] = sgn; }
    __syncthreads();

    // 2 samples per block; one thread finishes each sample's 16-det LSE
    if (tid < 2) {
        const int sample = blockIdx.x * 2 + tid;
        if (sample < n_samples) {
            const int base = tid * 2 * NDET;        // 32 quad entries per sample
            float xs[NDET];
            float gs[NDET];
            float xmax = -INFINITY;
            #pragma unroll
            for (int d = 0; d < NDET; ++d) {
                xs[d] = sx[base + 2 * d] + sx[base + 2 * d + 1];
                gs[d] = ss[base + 2 * d] * ss[base + 2 * d + 1];
                xmax  = fmaxf(xmax, xs[d]);
            }
            float sum = 0.0f;
            #pragma unroll
            for (int d = 0; d < NDET; ++d)
                sum += gs[d] * __expf(xs[d] - xmax) * w[d];
            out[sample] = __logf(fabsf(sum)) + xmax;
            out[n_samples + sample] = (sum > 0.0f) ? 1.0f : ((sum < 0.0f) ? -1.0f : 0.0f);
        }
    }
}

extern "C" void kernel_launch(void* const* d_in, const int* in_sizes, int n_in,
                              void* d_out, int out_size, void* d_ws, size_t ws_size,
                              hipStream_t stream)
{
    const float* a = (const float*)d_in[0];
    const float* b = (const float*)d_in[1];
    const float* w = (const float*)d_in[2];
    float* out = (float*)d_out;

    const int n_samples = in_sizes[0] / (NDET * NDIM * NDIM);
    const int blocks = (n_samples + 1) / 2;   // 2 samples (64 matrices) per block
    logabssumdet_kernel<<<blocks, 256, 0, stream>>>(a, b, w, out, n_samples);
}